// Round 17
// baseline (4085.986 us; speedup 1.0000x reference)
//
#include <hip/hip_runtime.h>
#include <hip/hip_fp16.h>

#define HD    256
#define TENC  15
#define PLEN  45
#define MROW  32
#define NTHR  256
#define NBLK  (32768 / MROW)   // 1024 blocks, 3 resident per CU (reg-budget 170)

typedef __attribute__((ext_vector_type(16))) float     f32x16;
typedef __attribute__((ext_vector_type(8)))  _Float16  f16x8;

#define MFMAH __builtin_amdgcn_mfma_f32_32x32x16_f16

__device__ __forceinline__ float fast_sig(float x) {
    float e = __builtin_amdgcn_exp2f(-1.44269504088896f * x);
    return __builtin_amdgcn_rcpf(1.f + e);
}
__device__ __forceinline__ float fast_tanh(float x) {
    float e = __builtin_amdgcn_exp2f(-2.88539008177793f * x);
    return (1.f - e) * __builtin_amdgcn_rcpf(1.f + e);
}

// Transpose W[n_gcols][256] f32 -> fp16 wave-burst layout:
// dst[seg*65536 + ((gc8*16 + kk)*64 + hi*32 + rowA)*8 + e]
__global__ void xpose_w_kernel(const float* __restrict__ src,
                               _Float16* __restrict__ dst, int n_gcols) {
    int t = blockIdx.x * blockDim.x + threadIdx.x;
    if (t >= n_gcols * 32) return;
    int gcol = t >> 5, c8 = t & 31;
    int kk = c8 >> 1, hi = c8 & 1;
    const float* s = src + (size_t)gcol * HD + c8 * 8;
    int seg = gcol >> 8, gc = gcol & 255;
    size_t d = (size_t)seg * 65536 +
               ((size_t)(((gc >> 5) * 16 + kk) * 64 + hi * 32 + (gc & 31))) * 8;
    _Float16 v[8];
    #pragma unroll
    for (int e = 0; e < 8; ++e) v[e] = (_Float16)s[e];
    *(f16x8*)(dst + d) = *(f16x8*)v;
}

// outW [4][256] padded to 32 gate-cols, same layout
__global__ void xpose_ow_kernel(const float* __restrict__ src,
                                _Float16* __restrict__ dst) {
    int t = blockIdx.x * blockDim.x + threadIdx.x;
    if (t >= 32 * 32) return;
    int gcol = t >> 5, c8 = t & 31;
    int kk = c8 >> 1, hi = c8 & 1;
    _Float16 v[8];
    if (gcol < 4) {
        const float* s = src + (size_t)gcol * HD + c8 * 8;
        #pragma unroll
        for (int e = 0; e < 8; ++e) v[e] = (_Float16)s[e];
    } else {
        #pragma unroll
        for (int e = 0; e < 8; ++e) v[e] = (_Float16)0.f;
    }
    size_t d = ((size_t)(kk * 64 + hi * 32 + gcol)) * 8;
    *(f16x8*)(dst + d) = *(f16x8*)v;
}

// Swizzled byte offset into a [32][256] fp16 LDS tile (row stride 512B).
__device__ __forceinline__ int swz(int row, int col) {
    return row * 512 + ((((col >> 3) ^ row) & 31) << 4) + ((col & 7) << 1);
}

__global__ __launch_bounds__(NTHR, 3) void gru_main(
    const float* __restrict__ x,
    const float* __restrict__ eW, const float* __restrict__ eb,
    const _Float16* __restrict__ encWih, const _Float16* __restrict__ encWhh,
    const float* __restrict__ enc_bih, const float* __restrict__ enc_bhh,
    const _Float16* __restrict__ decEW, const float* __restrict__ dec_eb,
    const _Float16* __restrict__ decWih, const _Float16* __restrict__ decWhh,
    const float* __restrict__ dec_bih, const float* __restrict__ dec_bhh,
    const _Float16* __restrict__ outWt, const float* __restrict__ outb,
    float* __restrict__ out)
{
    __shared__ __align__(16) char ls_a[MROW * 512];   // 16KB fp16, swizzled
    __shared__ __align__(16) char ls_h[MROW * 512];   // 16KB fp16, swizzled
    __shared__ float ls_ew[HD * 4];
    __shared__ float ls_eb[HD];
    __shared__ float ls_bias[4 * HD];   // bR, bZ, bN(ih), bH(hh)
    __shared__ float ls_deb[HD];

    const int tid   = threadIdx.x;
    const int lane  = tid & 63;
    const int wv    = tid >> 6;        // 0..3
    const int rowA  = lane & 31;
    const int hi    = lane >> 5;
    const int col0  = wv * 64 + rowA;       // ct=0 gate column
    const int col1  = wv * 64 + 32 + rowA;  // ct=1 gate column
    const int nbase = blockIdx.x * MROW;

    for (int i = tid; i < HD * 4; i += NTHR) ls_ew[i] = eW[i];
    if (tid < HD) {
        ls_eb[tid]            = eb[tid];
        ls_bias[tid]          = enc_bih[tid] + enc_bhh[tid];
        ls_bias[HD + tid]     = enc_bih[HD + tid] + enc_bhh[HD + tid];
        ls_bias[2 * HD + tid] = enc_bih[2 * HD + tid];
        ls_bias[3 * HD + tid] = enc_bhh[2 * HD + tid];
    }
    for (int i = tid; i < MROW * 512 / 4; i += NTHR) ((unsigned int*)ls_h)[i] = 0u;

    float bR0, bR1, bZ0, bZ1, bN0, bN1, bH0, bH1;  // per-phase biases
    float deb0, deb1, bb;

    // Two-pass accumulators: 4 x f32x16 = 64 regs — the occupancy lever.
    f32x16 accA[2], accB[2];

    const char* pa = ls_a + rowA * 512;
    const char* ph = ls_h + rowA * 512;

    auto bcast = [](float v) {
        f32x16 a;
        #pragma unroll
        for (int i = 0; i < 16; ++i) a[i] = v;
        return a;
    };

    // pass1: accA = bR + a@Wr + h@Ur ; accB = bH + h@Un   (streams r, Ur, Un)
    auto pass1 = [&](const _Float16* Wi, const _Float16* Wh) {
        accA[0] = bcast(bR0); accA[1] = bcast(bR1);
        accB[0] = bcast(bH0); accB[1] = bcast(bH1);
        const _Float16* bi0 = Wi + (2 * wv) * 8192 + lane * 8;
        const _Float16* bh0 = Wh + (2 * wv) * 8192 + lane * 8;
        #pragma unroll 2
        for (int kk = 0; kk < 16; ++kk) {
            const int sh = (((kk * 2 + hi) ^ rowA) & 31) << 4;
            f16x8 ax = *(const f16x8*)(pa + sh);
            f16x8 ah = *(const f16x8*)(ph + sh);
            f16x8 b0 = *(const f16x8*)(bi0 + kk * 512);           // Wr ct0
            f16x8 b1 = *(const f16x8*)(bi0 + kk * 512 + 8192);    // Wr ct1
            accA[0] = MFMAH(ax, b0, accA[0], 0, 0, 0);
            accA[1] = MFMAH(ax, b1, accA[1], 0, 0, 0);
            b0 = *(const f16x8*)(bh0 + kk * 512);                 // Ur ct0
            b1 = *(const f16x8*)(bh0 + kk * 512 + 8192);          // Ur ct1
            accA[0] = MFMAH(ah, b0, accA[0], 0, 0, 0);
            accA[1] = MFMAH(ah, b1, accA[1], 0, 0, 0);
            b0 = *(const f16x8*)(bh0 + kk * 512 + 131072);        // Un ct0
            b1 = *(const f16x8*)(bh0 + kk * 512 + 131072 + 8192); // Un ct1
            accB[0] = MFMAH(ah, b0, accB[0], 0, 0, 0);
            accB[1] = MFMAH(ah, b1, accB[1], 0, 0, 0);
        }
    };

    // mid: accB := sig(accA) * accB + bN   (accA freed for pass2)
    auto mid = [&]() {
        #pragma unroll
        for (int q = 0; q < 16; ++q) {
            accB[0][q] = fmaf(fast_sig(accA[0][q]), accB[0][q], bN0);
            accB[1][q] = fmaf(fast_sig(accA[1][q]), accB[1][q], bN1);
        }
    };

    // pass2: accA = bZ + a@Wz + h@Uz ; accB += a@Wn   (streams z, Uz, Wn)
    auto pass2 = [&](const _Float16* Wi, const _Float16* Wh) {
        accA[0] = bcast(bZ0); accA[1] = bcast(bZ1);
        const _Float16* bi0 = Wi + (2 * wv) * 8192 + lane * 8;
        const _Float16* bh0 = Wh + (2 * wv) * 8192 + lane * 8;
        #pragma unroll 2
        for (int kk = 0; kk < 16; ++kk) {
            const int sh = (((kk * 2 + hi) ^ rowA) & 31) << 4;
            f16x8 ax = *(const f16x8*)(pa + sh);
            f16x8 ah = *(const f16x8*)(ph + sh);
            f16x8 b0 = *(const f16x8*)(bi0 + kk * 512 + 65536);   // Wz ct0
            f16x8 b1 = *(const f16x8*)(bi0 + kk * 512 + 65536 + 8192);
            accA[0] = MFMAH(ax, b0, accA[0], 0, 0, 0);
            accA[1] = MFMAH(ax, b1, accA[1], 0, 0, 0);
            b0 = *(const f16x8*)(bh0 + kk * 512 + 65536);         // Uz ct0
            b1 = *(const f16x8*)(bh0 + kk * 512 + 65536 + 8192);
            accA[0] = MFMAH(ah, b0, accA[0], 0, 0, 0);
            accA[1] = MFMAH(ah, b1, accA[1], 0, 0, 0);
            b0 = *(const f16x8*)(bi0 + kk * 512 + 131072);        // Wn ct0
            b1 = *(const f16x8*)(bi0 + kk * 512 + 131072 + 8192);
            accB[0] = MFMAH(ax, b0, accB[0], 0, 0, 0);
            accB[1] = MFMAH(ax, b1, accB[1], 0, 0, 0);
        }
    };

    // fused final+write (AFTER barrier B1): z = sig(accA), n = tanh(accB),
    // h_new = n + z*(h_old - n), ls_h updated IN PLACE (own elements only).
    auto final_write = [&]() {
        #pragma unroll
        for (int q = 0; q < 16; ++q) {
            int row = (q & 3) + ((q >> 2) << 3) + (hi << 2);
            _Float16* p0 = (_Float16*)(ls_h + swz(row, col0));
            _Float16* p1 = (_Float16*)(ls_h + swz(row, col1));
            float h0 = (float)*p0, h1 = (float)*p1;
            float z0 = fast_sig(accA[0][q]);
            float n0 = fast_tanh(accB[0][q]);
            float z1 = fast_sig(accA[1][q]);
            float n1 = fast_tanh(accB[1][q]);
            *p0 = (_Float16)fmaf(z0, h0 - n0, n0);
            *p1 = (_Float16)fmaf(z1, h1 - n1, n1);
        }
    };

    auto embed_step = [&](int t) {
        int row = tid & 31;
        int c0  = (tid >> 5) * 32;
        const float4 xv = *(const float4*)(x + ((size_t)(nbase + row) * TENC + t) * 4);
        #pragma unroll 8
        for (int j = 0; j < 32; ++j) {
            int c = c0 + j;
            const float* wp = &ls_ew[c * 4];
            float v = fmaf(xv.x, wp[0], fmaf(xv.y, wp[1],
                      fmaf(xv.z, wp[2], fmaf(xv.w, wp[3], ls_eb[c]))));
            *(_Float16*)(ls_a + swz(row, c)) = (_Float16)fmaxf(v, 0.f);
        }
    };

    // dec_in = relu(h @ dec_embed_W^T + deb) -> ls_a
    auto dec_embed = [&]() {
        f32x16 o0 = bcast(deb0), o1 = bcast(deb1);
        const _Float16* be = decEW + (2 * wv) * 8192 + lane * 8;
        #pragma unroll 2
        for (int kk = 0; kk < 16; ++kk) {
            const int sh = (((kk * 2 + hi) ^ rowA) & 31) << 4;
            f16x8 a = *(const f16x8*)(ph + sh);
            f16x8 b0 = *(const f16x8*)(be + kk * 512);
            f16x8 b1 = *(const f16x8*)(be + kk * 512 + 8192);
            o0 = MFMAH(a, b0, o0, 0, 0, 0);
            o1 = MFMAH(a, b1, o1, 0, 0, 0);
        }
        #pragma unroll
        for (int q = 0; q < 16; ++q) {
            int row = (q & 3) + ((q >> 2) << 3) + (hi << 2);
            *(_Float16*)(ls_a + swz(row, col0)) = (_Float16)fmaxf(o0[q], 0.f);
            *(_Float16*)(ls_a + swz(row, col1)) = (_Float16)fmaxf(o1[q], 0.f);
        }
    };

    // out = h @ out_W^T + out_b; wave 0 only (32 rows, 4 real cols)
    auto out_layer = [&](int t) {
        if (wv == 0) {
            f32x16 o = bcast(bb);
            const _Float16* bo = outWt + lane * 8;
            #pragma unroll 2
            for (int kk = 0; kk < 16; ++kk) {
                const int sh = (((kk * 2 + hi) ^ rowA) & 31) << 4;
                f16x8 a = *(const f16x8*)(ph + sh);
                f16x8 b = *(const f16x8*)(bo + kk * 512);
                o = MFMAH(a, b, o, 0, 0, 0);
            }
            if (rowA < 4) {
                #pragma unroll
                for (int q = 0; q < 16; ++q) {
                    int row = (q & 3) + ((q >> 2) << 3) + (hi << 2);
                    out[((size_t)(nbase + row) * PLEN + t) * 4 + rowA] = o[q];
                }
            }
        }
    };

    // ---- prologue ----
    __syncthreads();             // staging + ls_h zero visible
    bR0 = ls_bias[col0];          bR1 = ls_bias[col1];
    bZ0 = ls_bias[HD + col0];     bZ1 = ls_bias[HD + col1];
    bN0 = ls_bias[2 * HD + col0]; bN1 = ls_bias[2 * HD + col1];
    bH0 = ls_bias[3 * HD + col0]; bH1 = ls_bias[3 * HD + col1];
    embed_step(0);
    __syncthreads();             // ls_a ready

    // ---- encoder: 2 barriers/step ----
    for (int t = 0; t < TENC; ++t) {
        pass1(encWih, encWhh);
        mid();
        pass2(encWih, encWhh);
        __syncthreads();         // B1: all ls_a/ls_h reads done
        final_write();           // h_t in place
        if (t + 1 < TENC) embed_step(t + 1);
        __syncthreads();         // B2: new h + next embed visible
    }

    // ---- encoder -> decoder transition ----
    if (tid < HD) {
        ls_bias[tid]          = dec_bih[tid] + dec_bhh[tid];
        ls_bias[HD + tid]     = dec_bih[HD + tid] + dec_bhh[HD + tid];
        ls_bias[2 * HD + tid] = dec_bih[2 * HD + tid];
        ls_bias[3 * HD + tid] = dec_bhh[2 * HD + tid];
        ls_deb[tid]           = dec_eb[tid];
    }
    __syncthreads();
    bR0 = ls_bias[col0];          bR1 = ls_bias[col1];
    bZ0 = ls_bias[HD + col0];     bZ1 = ls_bias[HD + col1];
    bN0 = ls_bias[2 * HD + col0]; bN1 = ls_bias[2 * HD + col1];
    bH0 = ls_bias[3 * HD + col0]; bH1 = ls_bias[3 * HD + col1];
    deb0 = ls_deb[col0];          deb1 = ls_deb[col1];
    bb   = (rowA < 4) ? outb[rowA] : 0.f;
    dec_embed();                 // dec_in0 from h_enc
    __syncthreads();

    // ---- decoder: 3 barriers/step ----
    for (int t = 0; t < PLEN; ++t) {
        pass1(decWih, decWhh);
        mid();
        pass2(decWih, decWhh);
        __syncthreads();         // B1: all reads of ls_a/ls_h done
        final_write();           // h_t in place
        __syncthreads();         // B2: h_t visible
        dec_embed();             // dec_in t+1 -> ls_a
        __syncthreads();         // B3: ls_a ready
        out_layer(t);            // reads ls_h (stable until next final_write)
    }
}

extern "C" void kernel_launch(void* const* d_in, const int* in_sizes, int n_in,
                              void* d_out, int out_size, void* d_ws, size_t ws_size,
                              hipStream_t stream) {
    const float* x       = (const float*)d_in[0];
    const float* eW      = (const float*)d_in[1];
    const float* eb      = (const float*)d_in[2];
    const float* encWihf = (const float*)d_in[3];
    const float* encWhhf = (const float*)d_in[4];
    const float* enc_bih = (const float*)d_in[5];
    const float* enc_bhh = (const float*)d_in[6];
    const float* decEWf  = (const float*)d_in[7];
    const float* dec_eb  = (const float*)d_in[8];
    const float* decWihf = (const float*)d_in[9];
    const float* decWhhf = (const float*)d_in[10];
    const float* dec_bih = (const float*)d_in[11];
    const float* dec_bhh = (const float*)d_in[12];
    const float* outW    = (const float*)d_in[13];
    const float* outb    = (const float*)d_in[14];

    _Float16* ws = (_Float16*)d_ws;
    _Float16* hWih_e = ws;                  // 3*H*H each
    _Float16* hWhh_e = ws + 196608;
    _Float16* hWih_d = ws + 2 * 196608;
    _Float16* hWhh_d = ws + 3 * 196608;
    _Float16* hEW_d  = ws + 4 * 196608;     // H*H
    _Float16* hOWt   = ws + 4 * 196608 + 65536;  // 32*H

    const int t1 = 768 * 32;
    const int t2 = 256 * 32;
    xpose_w_kernel<<<(t1 + 255) / 256, 256, 0, stream>>>(encWihf, hWih_e, 768);
    xpose_w_kernel<<<(t1 + 255) / 256, 256, 0, stream>>>(encWhhf, hWhh_e, 768);
    xpose_w_kernel<<<(t1 + 255) / 256, 256, 0, stream>>>(decWihf, hWih_d, 768);
    xpose_w_kernel<<<(t1 + 255) / 256, 256, 0, stream>>>(decWhhf, hWhh_d, 768);
    xpose_w_kernel<<<(t2 + 255) / 256, 256, 0, stream>>>(decEWf,  hEW_d,  256);
    xpose_ow_kernel<<<4, 256, 0, stream>>>(outW, hOWt);

    gru_main<<<NBLK, NTHR, 0, stream>>>(
        x, eW, eb, hWih_e, hWhh_e, enc_bih, enc_bhh,
        hEW_d, dec_eb, hWih_d, hWhh_d, dec_bih, dec_bhh,
        hOWt, outb, (float*)d_out);
}

// Round 18
// 2241.812 us; speedup vs baseline: 1.8226x; 1.8226x over previous
//
#include <hip/hip_runtime.h>
#include <hip/hip_fp16.h>

#define HD    256
#define TENC  15
#define PLEN  45
#define MROW  64
#define NTHR  512
#define NBLK  (32768 / MROW)   // 512 blocks

typedef __attribute__((ext_vector_type(16))) float     f32x16;
typedef __attribute__((ext_vector_type(8)))  _Float16  f16x8;

#define MFMAH __builtin_amdgcn_mfma_f32_32x32x16_f16

__device__ __forceinline__ float fast_sig(float x) {
    float e = __builtin_amdgcn_exp2f(-1.44269504088896f * x);
    return __builtin_amdgcn_rcpf(1.f + e);
}
__device__ __forceinline__ float fast_tanh(float x) {
    float e = __builtin_amdgcn_exp2f(-2.88539008177793f * x);
    return (1.f - e) * __builtin_amdgcn_rcpf(1.f + e);
}

// Transpose W[n_gcols][256] f32 -> fp16 wave-burst layout:
// dst[seg*65536 + ((gc8*16 + kk)*64 + hi*32 + rowA)*8 + e]
__global__ void xpose_w_kernel(const float* __restrict__ src,
                               _Float16* __restrict__ dst, int n_gcols) {
    int t = blockIdx.x * blockDim.x + threadIdx.x;
    if (t >= n_gcols * 32) return;
    int gcol = t >> 5, c8 = t & 31;
    int kk = c8 >> 1, hi = c8 & 1;
    const float* s = src + (size_t)gcol * HD + c8 * 8;
    int seg = gcol >> 8, gc = gcol & 255;
    size_t d = (size_t)seg * 65536 +
               ((size_t)(((gc >> 5) * 16 + kk) * 64 + hi * 32 + (gc & 31))) * 8;
    _Float16 v[8];
    #pragma unroll
    for (int e = 0; e < 8; ++e) v[e] = (_Float16)s[e];
    *(f16x8*)(dst + d) = *(f16x8*)v;
}

// outW [4][256] padded to 32 gate-cols, same layout
__global__ void xpose_ow_kernel(const float* __restrict__ src,
                                _Float16* __restrict__ dst) {
    int t = blockIdx.x * blockDim.x + threadIdx.x;
    if (t >= 32 * 32) return;
    int gcol = t >> 5, c8 = t & 31;
    int kk = c8 >> 1, hi = c8 & 1;
    _Float16 v[8];
    if (gcol < 4) {
        const float* s = src + (size_t)gcol * HD + c8 * 8;
        #pragma unroll
        for (int e = 0; e < 8; ++e) v[e] = (_Float16)s[e];
    } else {
        #pragma unroll
        for (int e = 0; e < 8; ++e) v[e] = (_Float16)0.f;
    }
    size_t d = ((size_t)(kk * 64 + hi * 32 + gcol)) * 8;
    *(f16x8*)(dst + d) = *(f16x8*)v;
}

// Swizzled byte offset into a [64][256] fp16 LDS tile (row stride 512B).
__device__ __forceinline__ int swz(int row, int col) {
    return row * 512 + ((((col >> 3) ^ row) & 31) << 4) + ((col & 7) << 1);
}

__global__ __launch_bounds__(NTHR, 2) void gru_main(
    const float* __restrict__ x,
    const float* __restrict__ eW, const float* __restrict__ eb,
    const _Float16* __restrict__ encWih, const _Float16* __restrict__ encWhh,
    const float* __restrict__ enc_bih, const float* __restrict__ enc_bhh,
    const _Float16* __restrict__ decEW, const float* __restrict__ dec_eb,
    const _Float16* __restrict__ decWih, const _Float16* __restrict__ decWhh,
    const float* __restrict__ dec_bih, const float* __restrict__ dec_bhh,
    const _Float16* __restrict__ outWt, const float* __restrict__ outb,
    float* __restrict__ out)
{
    __shared__ __align__(16) char ls_a[MROW * 512];   // 32KB fp16, swizzled
    __shared__ __align__(16) char ls_h[MROW * 512];   // 32KB fp16, swizzled
    __shared__ float ls_ew[HD * 4];
    __shared__ float ls_eb[HD];
    __shared__ float ls_bias[4 * HD];   // bR, bZ, bN(ih), bH(hh)
    __shared__ float ls_deb[HD];

    const int tid   = threadIdx.x;
    const int lane  = tid & 63;
    const int wv    = tid >> 6;        // 0..7
    const int rowA  = lane & 31;
    const int hi    = lane >> 5;
    const int col   = wv * 32 + rowA;  // this lane's gate column
    const int nbase = blockIdx.x * MROW;

    for (int i = tid; i < HD * 4; i += NTHR) ls_ew[i] = eW[i];
    if (tid < HD) {
        ls_eb[tid]            = eb[tid];
        ls_bias[tid]          = enc_bih[tid] + enc_bhh[tid];
        ls_bias[HD + tid]     = enc_bih[HD + tid] + enc_bhh[HD + tid];
        ls_bias[2 * HD + tid] = enc_bih[2 * HD + tid];
        ls_bias[3 * HD + tid] = enc_bhh[2 * HD + tid];
    }
    for (int i = tid; i < MROW * 512 / 4; i += NTHR) ((unsigned int*)ls_h)[i] = 0u;

    // h carried as packed fp16 pairs: 2 rowtiles x 8 half2 = 16 regs (|h|<=1).
    __half2 hpk[16];
    #pragma unroll
    for (int i = 0; i < 16; ++i) hpk[i] = __floats2half2_rn(0.f, 0.f);

    float bR, bZ, bN, bH;   // current-phase biases (enc, then dec)
    float deb, bb;

    f32x16 accR0, accR1, accZ0, accZ1, accN10, accN11, accN20, accN21;

    const char* pa = ls_a + rowA * 512;
    const char* ph = ls_h + rowA * 512;

    auto bcast = [](float v) {
        f32x16 a;
        #pragma unroll
        for (int i = 0; i < 16; ++i) a[i] = v;
        return a;
    };

    // gates: acc init = bias; single sweep of all 6 weight streams, unroll 2.
    // s_setprio(1) keeps the matrix pipe favored while other waves run
    // epilogue/embed phases (T5; per-wave role asymmetry exists here).
    auto gates = [&](const _Float16* Wi, const _Float16* Wh) {
        accR0 = bcast(bR);  accR1 = accR0;
        accZ0 = bcast(bZ);  accZ1 = accZ0;
        accN10 = bcast(bN); accN11 = accN10;
        accN20 = bcast(bH); accN21 = accN20;
        const _Float16* bi = Wi + wv * 8192 + lane * 8;
        const _Float16* bh = Wh + wv * 8192 + lane * 8;
        __builtin_amdgcn_s_setprio(1);
        #pragma unroll 2
        for (int kk = 0; kk < 16; ++kk) {
            const int sh = (((kk * 2 + hi) ^ rowA) & 31) << 4;
            f16x8 ax0 = *(const f16x8*)(pa + sh);
            f16x8 ax1 = *(const f16x8*)(pa + 16384 + sh);
            f16x8 ah0 = *(const f16x8*)(ph + sh);
            f16x8 ah1 = *(const f16x8*)(ph + 16384 + sh);
            const _Float16* ki = bi + kk * 512;
            const _Float16* kh = bh + kk * 512;
            f16x8 bri = *(const f16x8*)(ki);
            f16x8 bzi = *(const f16x8*)(ki + 65536);
            f16x8 bni = *(const f16x8*)(ki + 131072);
            f16x8 brh = *(const f16x8*)(kh);
            f16x8 bzh = *(const f16x8*)(kh + 65536);
            f16x8 bnh = *(const f16x8*)(kh + 131072);
            accR0  = MFMAH(ax0, bri, accR0, 0, 0, 0);
            accR1  = MFMAH(ax1, bri, accR1, 0, 0, 0);
            accZ0  = MFMAH(ax0, bzi, accZ0, 0, 0, 0);
            accZ1  = MFMAH(ax1, bzi, accZ1, 0, 0, 0);
            accN10 = MFMAH(ax0, bni, accN10, 0, 0, 0);
            accN11 = MFMAH(ax1, bni, accN11, 0, 0, 0);
            accR0  = MFMAH(ah0, brh, accR0, 0, 0, 0);
            accR1  = MFMAH(ah1, brh, accR1, 0, 0, 0);
            accZ0  = MFMAH(ah0, bzh, accZ0, 0, 0, 0);
            accZ1  = MFMAH(ah1, bzh, accZ1, 0, 0, 0);
            accN20 = MFMAH(ah0, bnh, accN20, 0, 0, 0);
            accN21 = MFMAH(ah1, bnh, accN21, 0, 0, 0);
        }
        __builtin_amdgcn_s_setprio(0);
    };

    // C/D 32x32 layout: col = lane&31, row = (q&3) + 8*(q>>2) + 4*hi
    auto upd_tile = [&](f32x16& aR, f32x16& aZ, f32x16& aN1, f32x16& aN2, int rt) {
        #pragma unroll
        for (int q = 0; q < 16; q += 2) {
            float2 hv = __half22float2(hpk[rt * 8 + (q >> 1)]);
            float r0 = fast_sig(aR[q]);
            float z0 = fast_sig(aZ[q]);
            float n0 = fast_tanh(fmaf(r0, aN2[q], aN1[q]));
            float h0 = fmaf(z0, hv.x - n0, n0);
            float r1 = fast_sig(aR[q + 1]);
            float z1 = fast_sig(aZ[q + 1]);
            float n1 = fast_tanh(fmaf(r1, aN2[q + 1], aN1[q + 1]));
            float h1 = fmaf(z1, hv.y - n1, n1);
            hpk[rt * 8 + (q >> 1)] = __floats2half2_rn(h0, h1);
        }
    };

    auto write_h = [&]() {
        #pragma unroll
        for (int rt = 0; rt < 2; ++rt)
            #pragma unroll
            for (int q = 0; q < 16; q += 2) {
                unsigned int u = *(unsigned int*)&hpk[rt * 8 + (q >> 1)];
                int row = rt * 32 + (q & 3) + ((q >> 2) << 3) + (hi << 2);
                *(unsigned short*)(ls_h + swz(row, col))     = (unsigned short)u;
                *(unsigned short*)(ls_h + swz(row + 1, col)) = (unsigned short)(u >> 16);
            }
    };

    auto embed_step = [&](int t) {
        int row = tid & 63;
        int c0  = (tid >> 6) * 32;
        const float4 xv = *(const float4*)(x + ((size_t)(nbase + row) * TENC + t) * 4);
        #pragma unroll 8
        for (int j = 0; j < 32; ++j) {
            int c = c0 + j;
            const float* wp = &ls_ew[c * 4];
            float v = fmaf(xv.x, wp[0], fmaf(xv.y, wp[1],
                      fmaf(xv.z, wp[2], fmaf(xv.w, wp[3], ls_eb[c]))));
            *(_Float16*)(ls_a + swz(row, c)) = (_Float16)fmaxf(v, 0.f);
        }
    };

    // dec_in = relu(h @ dec_embed_W^T + deb) -> ls_a
    auto dec_embed = [&]() {
        f32x16 o0 = bcast(deb), o1 = o0;
        const _Float16* be = decEW + wv * 8192 + lane * 8;
        __builtin_amdgcn_s_setprio(1);
        #pragma unroll 2
        for (int kk = 0; kk < 16; ++kk) {
            const int sh = (((kk * 2 + hi) ^ rowA) & 31) << 4;
            f16x8 a0 = *(const f16x8*)(ph + sh);
            f16x8 a1 = *(const f16x8*)(ph + 16384 + sh);
            f16x8 b = *(const f16x8*)(be + kk * 512);
            o0 = MFMAH(a0, b, o0, 0, 0, 0);
            o1 = MFMAH(a1, b, o1, 0, 0, 0);
        }
        __builtin_amdgcn_s_setprio(0);
        #pragma unroll
        for (int rt = 0; rt < 2; ++rt) {
            const f32x16& o = rt ? o1 : o0;
            #pragma unroll
            for (int q = 0; q < 16; ++q) {
                int row = rt * 32 + (q & 3) + ((q >> 2) << 3) + (hi << 2);
                *(_Float16*)(ls_a + swz(row, col)) = (_Float16)fmaxf(o[q], 0.f);
            }
        }
    };

    // out = h @ out_W^T + out_b; rowtile 0 -> wave 0, rowtile 1 -> wave 4
    auto out_layer = [&](int t) {
        if ((wv & 3) == 0) {
            const int rt = wv >> 2;
            f32x16 o = bcast(bb);
            const char* pH = ph + rt * 16384;
            const _Float16* bo = outWt + lane * 8;
            #pragma unroll 2
            for (int kk = 0; kk < 16; ++kk) {
                const int sh = (((kk * 2 + hi) ^ rowA) & 31) << 4;
                f16x8 a = *(const f16x8*)(pH + sh);
                f16x8 b = *(const f16x8*)(bo + kk * 512);
                o = MFMAH(a, b, o, 0, 0, 0);
            }
            if (rowA < 4) {
                #pragma unroll
                for (int q = 0; q < 16; ++q) {
                    int row = rt * 32 + (q & 3) + ((q >> 2) << 3) + (hi << 2);
                    out[((size_t)(nbase + row) * PLEN + t) * 4 + rowA] = o[q];
                }
            }
        }
    };

    // ---- prologue ----
    __syncthreads();             // staging + ls_h zero visible
    bR = ls_bias[col];
    bZ = ls_bias[HD + col];
    bN = ls_bias[2 * HD + col];
    bH = ls_bias[3 * HD + col];
    embed_step(0);
    __syncthreads();             // ls_a ready

    // ---- encoder: 2 barriers/step ----
    for (int t = 0; t < TENC; ++t) {
        gates(encWih, encWhh);
        upd_tile(accR0, accZ0, accN10, accN20, 0);
        upd_tile(accR1, accZ1, accN11, accN21, 1);
        __syncthreads();         // all ls_a/ls_h reads done
        write_h();
        if (t + 1 < TENC) embed_step(t + 1);
        __syncthreads();         // new h + next embed visible
    }

    // ---- encoder -> decoder transition ----
    if (tid < HD) {
        ls_bias[tid]          = dec_bih[tid] + dec_bhh[tid];
        ls_bias[HD + tid]     = dec_bih[HD + tid] + dec_bhh[HD + tid];
        ls_bias[2 * HD + tid] = dec_bih[2 * HD + tid];
        ls_bias[3 * HD + tid] = dec_bhh[2 * HD + tid];
        ls_deb[tid]           = dec_eb[tid];
    }
    __syncthreads();
    bR = ls_bias[col];
    bZ = ls_bias[HD + col];
    bN = ls_bias[2 * HD + col];
    bH = ls_bias[3 * HD + col];
    deb = ls_deb[col];
    bb  = (rowA < 4) ? outb[rowA] : 0.f;
    dec_embed();                 // dec_in0 from h_enc
    __syncthreads();

    // ---- decoder: 3 barriers/step; out_layer hides under next gates ----
    for (int t = 0; t < PLEN; ++t) {
        gates(decWih, decWhh);   // reads ls_a (dec_in t), ls_h (h_{t-1})
        upd_tile(accR0, accZ0, accN10, accN20, 0);
        upd_tile(accR1, accZ1, accN11, accN21, 1);
        __syncthreads();         // B1: reads done
        write_h();               // h_t
        __syncthreads();         // B2: h_t visible
        dec_embed();             // dec_in t+1 -> ls_a
        __syncthreads();         // B3: ls_a ready
        out_layer(t);            // reads ls_h (stable until next write_h)
    }
}

extern "C" void kernel_launch(void* const* d_in, const int* in_sizes, int n_in,
                              void* d_out, int out_size, void* d_ws, size_t ws_size,
                              hipStream_t stream) {
    const float* x       = (const float*)d_in[0];
    const float* eW      = (const float*)d_in[1];
    const float* eb      = (const float*)d_in[2];
    const float* encWihf = (const float*)d_in[3];
    const float* encWhhf = (const float*)d_in[4];
    const float* enc_bih = (const float*)d_in[5];
    const float* enc_bhh = (const float*)d_in[6];
    const float* decEWf  = (const float*)d_in[7];
    const float* dec_eb  = (const float*)d_in[8];
    const float* decWihf = (const float*)d_in[9];
    const float* decWhhf = (const float*)d_in[10];
    const float* dec_bih = (const float*)d_in[11];
    const float* dec_bhh = (const float*)d_in[12];
    const float* outW    = (const float*)d_in[13];
    const float* outb    = (const float*)d_in[14];

    _Float16* ws = (_Float16*)d_ws;
    _Float16* hWih_e = ws;                  // 3*H*H each
    _Float16* hWhh_e = ws + 196608;
    _Float16* hWih_d = ws + 2 * 196608;
    _Float16* hWhh_d = ws + 3 * 196608;
    _Float16* hEW_d  = ws + 4 * 196608;     // H*H
    _Float16* hOWt   = ws + 4 * 196608 + 65536;  // 32*H

    const int t1 = 768 * 32;
    const int t2 = 256 * 32;
    xpose_w_kernel<<<(t1 + 255) / 256, 256, 0, stream>>>(encWihf, hWih_e, 768);
    xpose_w_kernel<<<(t1 + 255) / 256, 256, 0, stream>>>(encWhhf, hWhh_e, 768);
    xpose_w_kernel<<<(t1 + 255) / 256, 256, 0, stream>>>(decWihf, hWih_d, 768);
    xpose_w_kernel<<<(t1 + 255) / 256, 256, 0, stream>>>(decWhhf, hWhh_d, 768);
    xpose_w_kernel<<<(t2 + 255) / 256, 256, 0, stream>>>(decEWf,  hEW_d,  256);
    xpose_ow_kernel<<<4, 256, 0, stream>>>(outW, hOWt);

    gru_main<<<NBLK, NTHR, 0, stream>>>(
        x, eW, eb, hWih_e, hWhh_e, enc_bih, enc_bhh,
        hEW_d, dec_eb, hWih_d, hWhh_d, dec_bih, dec_bhh,
        hOWt, outb, (float*)d_out);
}